// Round 9
// baseline (730.797 us; speedup 1.0000x reference)
//
#include <hip/hip_runtime.h>
#include <hip/hip_bf16.h>
#include <math.h>

// N=500,000 nodes, E=16,000,000 edges, D_COEF=1, EPS=1e-12.
// Outputs (fp32, flat): v [N,2] then torque [N,1].
//
// R5 best split: phase1 (bin+sort) 145 us + phase2 (LDS u64 reduce) 119.
// R6..R13: every isolated phase-1 theory falsified (waves, DS atomics,
//   gather, cursor false sharing, occupancy/TLP). Phase 1 = ~145 us
//   per-CU floor, all pipes <16%. Phase 2 = ~90% of DS-u64-RMW floor.
// R14: the floors are on DISJOINT resources -> overlap. One fused
//   kernel: 245 consumer blocks (one/bin) + 512 producer blocks.
//   Edge chunks in 4 groups; producers write (bin,group) segments with
//   per-segment cursors, then threadfence + release done[group]++.
//   Consumers acquire-wait done[g]==target, reduce their segment.
//   Producers never wait on consumers -> deadlock-free; queued blocks
//   safe (producers self-sufficient, exit when chunks exhausted).
//   Segments: 245*4*17888*4B = 70.13 MB <= proven ws (R11 ran 70.23MB).
//
// ws (tier1): [0,4KB) seg cursors | [4KB,8KB) done[g*16] | bins segs.

#define NBITS_Q   21
#define Q_MASK    ((1u << NBITS_Q) - 1)
#define Q_SCALE   131072.0f            // 2^21 / 16
#define Q_INV     (1.0f / 131072.0f)
#define BIN_SHIFT 11
#define BIN_W     2048
#define NB        245                  // ceil(500000/2048)
#define K_BATCH   8192                 // edges per chunk
#define EPT       16                   // edges/thread (512 thr * 16 = 8192)
#define NTHREADS  512
#define NPROD     512                  // producer blocks
#define GROUPS    4
#define GSHIFT    9                    // 512 chunks per group
#define SEG_CAP   17888                // mean 17118 + 5.9 sigma
#define SCALE_F   524288.0f            // 2^19 fixed-point
#define INV_SCALE (1.0f / 524288.0f)
#define INV_2PI   0.15915494309189535f
// tier-2 (R12) constants
#define CAP       67584
#define CSTR      16

typedef unsigned uint4_v __attribute__((ext_vector_type(4)));

__global__ void init_fused(unsigned* __restrict__ ws_u32) {
    const int i = blockIdx.x * blockDim.x + threadIdx.x;
    if (i < 2048) ws_u32[i] = 0u;      // cur[1024] + done[1024 pad]
}

__global__ __launch_bounds__(512, 6) void fused_sort_reduce(
        const float* __restrict__ theta,
        const int4* __restrict__ src4, const int4* __restrict__ dst4,
        unsigned* __restrict__ bins, unsigned* __restrict__ cur,
        unsigned* __restrict__ done, const float* __restrict__ v0p,
        const float* __restrict__ w0p, float* __restrict__ out,
        int N, int E)
{
    __shared__ __align__(16) unsigned char pool[45056];
    const int tid    = threadIdx.x;
    const int NCHUNK = (E + K_BATCH - 1) / K_BATCH;     // 1954

    if (blockIdx.x < NB) {
        // ======================= CONSUMER =======================
        float*              th  = (float*)pool;                       // 8KB
        unsigned long long* acc = (unsigned long long*)(pool + 8192); // 16KB
        const int b     = blockIdx.x;
        const int node0 = b * BIN_W;
        const int W     = min(BIN_W, N - node0);

        for (int j = tid; j < BIN_W; j += NTHREADS) {
            th[j]  = (j < W) ? theta[node0 + j] : 0.f;
            acc[j] = 0ull;
        }
        __syncthreads();

        for (int g = 0; g < GROUPS; ++g) {
            const unsigned target =
                (unsigned)min(1 << GSHIFT, NCHUNK - (g << GSHIFT));
            if (tid == 0) {
                while (__hip_atomic_load(&done[g * 16], __ATOMIC_ACQUIRE,
                                         __HIP_MEMORY_SCOPE_AGENT) < target)
                    __builtin_amdgcn_s_sleep(8);
            }
            __syncthreads();
            const unsigned craw = __hip_atomic_load(
                &cur[b * GROUPS + g], __ATOMIC_ACQUIRE,
                __HIP_MEMORY_SCOPE_AGENT);
            const int cnt = (int)(craw < (unsigned)SEG_CAP ? craw
                                                           : (unsigned)SEG_CAP);
            const unsigned* bp =
                bins + (size_t)(b * GROUPS + g) * SEG_CAP;

            const int CH = NTHREADS * 8;
            int i0 = 0;
            for (; i0 + CH <= cnt; i0 += CH) {
                const uint4_v ea = *(const uint4_v*)(bp + i0 + tid * 4);
                const uint4_v eb = *(const uint4_v*)(bp + i0 + NTHREADS * 4
                                                     + tid * 4);
                const unsigned ee[8] = {ea.x, ea.y, ea.z, ea.w,
                                        eb.x, eb.y, eb.z, eb.w};
#pragma unroll
                for (int k = 0; k < 8; ++k) {
                    const unsigned e = ee[k];
                    const unsigned l = e >> NBITS_Q;
                    const float ts = (float)(e & Q_MASK) * Q_INV - 8.0f;
                    const float r  = (ts - th[l]) * INV_2PI;
                    const float sn = __builtin_amdgcn_sinf(r);
                    const float cs = __builtin_amdgcn_cosf(r);
                    const unsigned cq =
                        (unsigned)((cs + 1.0f) * SCALE_F + 0.5f);
                    const unsigned sq =
                        (unsigned)((sn + 1.0f) * SCALE_F + 0.5f);
                    atomicAdd(&acc[l], (1ull << 56)
                              | ((unsigned long long)cq << 28)
                              | (unsigned long long)sq);
                }
            }
            for (int i = i0 + tid; i < cnt; i += NTHREADS) {
                const unsigned e = bp[i];
                const unsigned l = e >> NBITS_Q;
                const float ts = (float)(e & Q_MASK) * Q_INV - 8.0f;
                const float r  = (ts - th[l]) * INV_2PI;
                const float sn = __builtin_amdgcn_sinf(r);
                const float cs = __builtin_amdgcn_cosf(r);
                const unsigned cq = (unsigned)((cs + 1.0f) * SCALE_F + 0.5f);
                const unsigned sq = (unsigned)((sn + 1.0f) * SCALE_F + 0.5f);
                atomicAdd(&acc[l], (1ull << 56)
                          | ((unsigned long long)cq << 28)
                          | (unsigned long long)sq);
            }
        }
        __syncthreads();

        const float v0 = *v0p, w0 = *w0p;
        for (int j = tid; j < W; j += NTHREADS) {
            const float t  = th[j];
            const float rr = t * INV_2PI;
            const float sn = __builtin_amdgcn_sinf(rr);
            const float cs = __builtin_amdgcn_cosf(rr);
            ((float2*)out)[node0 + j] = make_float2(v0 * cs, v0 * sn);
            const unsigned long long P = acc[j];
            const float c  = (float)(unsigned)(P >> 56);
            const float xs =
                (float)(unsigned)((P >> 28) & 0xFFFFFFFull) * INV_SCALE - c;
            const float ys =
                (float)(unsigned)(P & 0xFFFFFFFull) * INV_SCALE - c;
            const float nrm = sqrtf(xs * xs + ys * ys);
            out[2 * N + node0 + j] = w0 * (ys / fmaxf(nrm, 1e-12f));
        }
    } else {
        // ======================= PRODUCER =======================
        unsigned*      sorted = (unsigned*)pool;            // 32KB
        unsigned char* sbin   = pool + 32768;               //  8KB
        unsigned*      hist   = (unsigned*)(pool + 40960);  //  1KB
        unsigned*      base_  = hist + 256;
        unsigned*      gbase  = base_ + 256;
        unsigned*      lcnt   = gbase + 256;                // ends 45056

        const int pid = blockIdx.x - NB;
        const int E4  = E >> 2;

        for (int c = pid; c < NCHUNK; c += NPROD) {
            const int g = c >> GSHIFT;
            if (tid < 256) { hist[tid] = 0u; lcnt[tid] = 0u; }
            __syncthreads();

            // A: src quads + theta gathers (MLP)
            const int base4 = c * (K_BATCH >> 2);
            int4 sQ[EPT / 4];
#pragma unroll
            for (int j = 0; j < EPT / 4; ++j) {
                const int idx4 = base4 + j * NTHREADS + tid;
                sQ[j] = (idx4 < E4) ? src4[idx4] : make_int4(0, 0, 0, 0);
            }
            float tq[EPT];
#pragma unroll
            for (int j = 0; j < EPT / 4; ++j) {
                tq[j * 4 + 0] = theta[sQ[j].x];
                tq[j * 4 + 1] = theta[sQ[j].y];
                tq[j * 4 + 2] = theta[sQ[j].z];
                tq[j * 4 + 3] = theta[sQ[j].w];
            }

            // B: dst quads, entries, histogram
            unsigned ent[EPT];
            unsigned bn[EPT];
#pragma unroll
            for (int j = 0; j < EPT / 4; ++j) {
                const int idx4 = base4 + j * NTHREADS + tid;
                const int q0   = j * 4;
                if (idx4 < E4) {
                    const int4 d = dst4[idx4];
                    const int dd[4] = {d.x, d.y, d.z, d.w};
#pragma unroll
                    for (int k = 0; k < 4; ++k) {
                        const unsigned bb = (unsigned)dd[k] >> BIN_SHIFT;
                        float qf = (tq[q0 + k] + 8.0f) * Q_SCALE + 0.5f;
                        qf = fminf(fmaxf(qf, 0.0f), 2097151.0f);
                        ent[q0 + k] =
                            ((unsigned)(dd[k] & (BIN_W - 1)) << NBITS_Q)
                            | (unsigned)qf;
                        bn[q0 + k] = bb;
                        atomicAdd(&hist[bb], 1u);
                    }
                } else {
#pragma unroll
                    for (int k = 0; k < 4; ++k) bn[q0 + k] = 0xFFu;
                }
            }
            __syncthreads();

            // C: single-wave scan + segment-cursor reservation
            if (tid < 64) {
                unsigned h[4];
#pragma unroll
                for (int k = 0; k < 4; ++k) h[k] = hist[tid * 4 + k];
                const unsigned tot = h[0] + h[1] + h[2] + h[3];
                unsigned s = tot;
#pragma unroll
                for (int off = 1; off < 64; off <<= 1) {
                    const unsigned y = __shfl_up(s, off);
                    if (tid >= off) s += y;
                }
                unsigned run = s - tot;
#pragma unroll
                for (int k = 0; k < 4; ++k) {
                    base_[tid * 4 + k] = run;
                    run += h[k];
                }
#pragma unroll
                for (int k = 0; k < 4; ++k)
                    if (h[k]) gbase[tid * 4 + k] =
                        atomicAdd(&cur[(tid * 4 + k) * GROUPS + g], h[k]);
            }
            __syncthreads();

            // D: LDS counting-sort scatter
#pragma unroll
            for (int q = 0; q < EPT; ++q) {
                if (bn[q] != 0xFFu) {
                    const unsigned bb  = bn[q];
                    const unsigned pos = base_[bb] + atomicAdd(&lcnt[bb], 1u);
                    sorted[pos] = ent[q];
                    sbin[pos]   = (unsigned char)bb;
                }
            }
            __syncthreads();

            // E: coalesced write-out into (bin,group) segment
            const int nval = min(K_BATCH, E - c * K_BATCH);
            for (int l = tid; l < nval; l += NTHREADS) {
                const unsigned bb = sbin[l];
                const unsigned gp = gbase[bb] + ((unsigned)l - base_[bb]);
                if (gp < (unsigned)SEG_CAP)
                    bins[(size_t)(bb * GROUPS + g) * SEG_CAP + gp] = sorted[l];
            }
            __syncthreads();

            // publish: all block stores are drained by the barrier;
            // tid0's device fence writes back, then release-count.
            if (tid == 0) {
                __threadfence();
                __hip_atomic_fetch_add(&done[g * 16], 1u, __ATOMIC_RELEASE,
                                       __HIP_MEMORY_SCOPE_AGENT);
            }
        }
    }
}

// ================= tier 2: proven R12 path (unfused) =================

__global__ void init_cursors(unsigned* __restrict__ curv, int cstride) {
    const int tid = threadIdx.x;
    for (int i = tid; i < 256 * CSTR; i += 256) curv[i] = 0u;
    __syncthreads();
    if (tid < NB) curv[tid * cstride] = (unsigned)tid * CAP;
}

__global__ __launch_bounds__(256) void bin_edges_sort(
        const float* __restrict__ theta,
        const int4* __restrict__ src4, const int4* __restrict__ dst4,
        unsigned* __restrict__ bins, unsigned* __restrict__ cursor,
        int E, int cstride)
{
    __shared__ unsigned      sorted[K_BATCH];
    __shared__ unsigned char sbin[K_BATCH];
    __shared__ unsigned      hist[256];
    __shared__ unsigned      base[256];
    __shared__ unsigned      gbase[256];
    __shared__ unsigned      lcnt[256];

    const int tid   = threadIdx.x;
    const int e0    = blockIdx.x * K_BATCH;
    const int nval  = min(K_BATCH, E - e0);
    const int E4    = E >> 2;
    const int base4 = e0 >> 2;

    hist[tid] = 0u;
    lcnt[tid] = 0u;
    __syncthreads();

    int4 sQ[8];
#pragma unroll
    for (int j = 0; j < 8; ++j) {
        const int idx4 = base4 + j * 256 + tid;
        sQ[j] = (idx4 < E4) ? src4[idx4] : make_int4(0, 0, 0, 0);
    }
    float tq[32];
#pragma unroll
    for (int j = 0; j < 8; ++j) {
        tq[j * 4 + 0] = theta[sQ[j].x];
        tq[j * 4 + 1] = theta[sQ[j].y];
        tq[j * 4 + 2] = theta[sQ[j].z];
        tq[j * 4 + 3] = theta[sQ[j].w];
    }

    unsigned ent[32];
    unsigned bn[32];
#pragma unroll
    for (int j = 0; j < 8; ++j) {
        const int idx4 = base4 + j * 256 + tid;
        const int q0   = j * 4;
        if (idx4 < E4) {
            const int4 d = dst4[idx4];
            const int dd[4] = {d.x, d.y, d.z, d.w};
#pragma unroll
            for (int k = 0; k < 4; ++k) {
                const unsigned b = (unsigned)dd[k] >> BIN_SHIFT;
                float qf = (tq[q0 + k] + 8.0f) * Q_SCALE + 0.5f;
                qf = fminf(fmaxf(qf, 0.0f), 2097151.0f);
                ent[q0 + k] = ((unsigned)(dd[k] & (BIN_W - 1)) << NBITS_Q)
                              | (unsigned)qf;
                bn[q0 + k]  = b;
                atomicAdd(&hist[b], 1u);
            }
        } else {
#pragma unroll
            for (int k = 0; k < 4; ++k) bn[q0 + k] = 0xFFu;
        }
    }
    __syncthreads();

    if (tid < 64) {
        unsigned h[4];
#pragma unroll
        for (int k = 0; k < 4; ++k) h[k] = hist[tid * 4 + k];
        const unsigned tot = h[0] + h[1] + h[2] + h[3];
        unsigned s = tot;
#pragma unroll
        for (int off = 1; off < 64; off <<= 1) {
            const unsigned y = __shfl_up(s, off);
            if (tid >= off) s += y;
        }
        unsigned run = s - tot;
#pragma unroll
        for (int k = 0; k < 4; ++k) {
            base[tid * 4 + k] = run;
            run += h[k];
        }
#pragma unroll
        for (int k = 0; k < 4; ++k)
            if (h[k]) gbase[tid * 4 + k] =
                atomicAdd(&cursor[(tid * 4 + k) * cstride], h[k]);
    }
    __syncthreads();

#pragma unroll
    for (int q = 0; q < 32; ++q) {
        if (bn[q] != 0xFFu) {
            const unsigned b   = bn[q];
            const unsigned pos = base[b] + atomicAdd(&lcnt[b], 1u);
            sorted[pos] = ent[q];
            sbin[pos]   = (unsigned char)b;
        }
    }
    __syncthreads();

    for (int l = tid; l < nval; l += 256) {
        const unsigned b    = sbin[l];
        const unsigned gpos = gbase[b] + ((unsigned)l - base[b]);
        if (gpos < (b + 1u) * CAP)
            bins[gpos] = sorted[l];
    }
}

__global__ __launch_bounds__(1024) void reduce_bins(
        const float* __restrict__ theta, const unsigned* __restrict__ bins,
        const unsigned* __restrict__ cursor, const float* __restrict__ v0p,
        const float* __restrict__ w0p, float* __restrict__ out,
        int N, int cstride)
{
    __shared__ float th[BIN_W];
    __shared__ unsigned long long acc[BIN_W];
    const int b     = blockIdx.x;
    const int tid   = threadIdx.x;
    const int node0 = b * BIN_W;
    const int W     = min(BIN_W, N - node0);

    for (int j = tid; j < BIN_W; j += 1024) {
        th[j]  = (j < W) ? theta[node0 + j] : 0.f;
        acc[j] = 0ull;
    }
    __syncthreads();

    const unsigned  base  = (unsigned)b * CAP;
    const int       count = (int)(cursor[b * cstride] - base);
    const unsigned* bp    = bins + base;

    const int CH = 1024 * 8;
    int i0 = 0;
    for (; i0 + CH <= count; i0 += CH) {
        const uint4_v ea = *(const uint4_v*)(bp + i0 + tid * 4);
        const uint4_v eb = *(const uint4_v*)(bp + i0 + 4096 + tid * 4);
        const unsigned ee[8] = {ea.x, ea.y, ea.z, ea.w, eb.x, eb.y, eb.z, eb.w};
#pragma unroll
        for (int k = 0; k < 8; ++k) {
            const unsigned e = ee[k];
            const unsigned l = e >> NBITS_Q;
            const float ts = (float)(e & Q_MASK) * Q_INV - 8.0f;
            const float r  = (ts - th[l]) * INV_2PI;
            const float sn = __builtin_amdgcn_sinf(r);
            const float cs = __builtin_amdgcn_cosf(r);
            const unsigned cq = (unsigned)((cs + 1.0f) * SCALE_F + 0.5f);
            const unsigned sq = (unsigned)((sn + 1.0f) * SCALE_F + 0.5f);
            atomicAdd(&acc[l], (1ull << 56) | ((unsigned long long)cq << 28)
                               | (unsigned long long)sq);
        }
    }
    for (int i = i0 + tid; i < count; i += 1024) {
        const unsigned e = bp[i];
        const unsigned l = e >> NBITS_Q;
        const float ts = (float)(e & Q_MASK) * Q_INV - 8.0f;
        const float r  = (ts - th[l]) * INV_2PI;
        const float sn = __builtin_amdgcn_sinf(r);
        const float cs = __builtin_amdgcn_cosf(r);
        const unsigned cq = (unsigned)((cs + 1.0f) * SCALE_F + 0.5f);
        const unsigned sq = (unsigned)((sn + 1.0f) * SCALE_F + 0.5f);
        atomicAdd(&acc[l], (1ull << 56) | ((unsigned long long)cq << 28)
                           | (unsigned long long)sq);
    }
    __syncthreads();

    const float v0 = *v0p, w0 = *w0p;
    for (int j = tid; j < W; j += 1024) {
        const float t  = th[j];
        const float rr = t * INV_2PI;
        const float sn = __builtin_amdgcn_sinf(rr);
        const float cs = __builtin_amdgcn_cosf(rr);
        ((float2*)out)[node0 + j] = make_float2(v0 * cs, v0 * sn);
        const unsigned long long P = acc[j];
        const float c  = (float)(unsigned)(P >> 56);
        const float xs = (float)(unsigned)((P >> 28) & 0xFFFFFFFull) * INV_SCALE - c;
        const float ys = (float)(unsigned)(P & 0xFFFFFFFull) * INV_SCALE - c;
        const float nrm = sqrtf(xs * xs + ys * ys);
        out[2 * N + node0 + j] = w0 * (ys / fmaxf(nrm, 1e-12f));
    }
}

// ---------- tier 3: fallback (round-2 kernels) ----------

__global__ void zero_ws_kernel(float4* __restrict__ ws, int n4) {
    int i = blockIdx.x * blockDim.x + threadIdx.x;
    if (i < n4) ws[i] = make_float4(0.f, 0.f, 0.f, 0.f);
}

__global__ void edge_kernel_fb(const float* __restrict__ theta,
                               const int4* __restrict__ src4,
                               const int4* __restrict__ dst4,
                               float2* __restrict__ acc, int E8) {
    int i = blockIdx.x * blockDim.x + threadIdx.x;
    if (i >= E8) return;
    const int4 s0 = src4[2 * i], s1 = src4[2 * i + 1];
    const int4 d0 = dst4[2 * i], d1 = dst4[2 * i + 1];
    const int ss[8] = {s0.x, s0.y, s0.z, s0.w, s1.x, s1.y, s1.z, s1.w};
    const int dd[8] = {d0.x, d0.y, d0.z, d0.w, d1.x, d1.y, d1.z, d1.w};
    float ts[8], td[8];
#pragma unroll
    for (int k = 0; k < 8; ++k) ts[k] = theta[ss[k]];
#pragma unroll
    for (int k = 0; k < 8; ++k) td[k] = theta[dd[k]];
#pragma unroll
    for (int k = 0; k < 8; ++k) {
        float sn, cs;
        __sincosf(ts[k] - td[k], &sn, &cs);
        atomicAdd(&acc[dd[k]].x, cs);
        atomicAdd(&acc[dd[k]].y, sn);
    }
}

__global__ void node_kernel_fb(const float* __restrict__ theta,
                               const float2* __restrict__ acc,
                               const float* __restrict__ v0p,
                               const float* __restrict__ w0p,
                               float* __restrict__ out, int N) {
    int i = blockIdx.x * blockDim.x + threadIdx.x;
    if (i >= N) return;
    const float v0 = *v0p, w0 = *w0p;
    float sn, cs;
    __sincosf(theta[i], &sn, &cs);
    ((float2*)out)[i] = make_float2(v0 * cs, v0 * sn);
    const float2 a = acc[i];
    const float nrm = sqrtf(a.x * a.x + a.y * a.y);
    out[2 * N + i] = w0 * (a.y / fmaxf(nrm, 1e-12f));
}

extern "C" void kernel_launch(void* const* d_in, const int* in_sizes, int n_in,
                              void* d_out, int out_size, void* d_ws, size_t ws_size,
                              hipStream_t stream) {
    const float* theta = (const float*)d_in[0];
    const int*   src   = (const int*)d_in[1];
    const int*   dst   = (const int*)d_in[2];
    const float* v0p   = (const float*)d_in[3];
    const float* w0p   = (const float*)d_in[4];
    float*       out   = (float*)d_out;

    const int N = in_sizes[0];   // 500,000
    const int E = in_sizes[1];   // 16,000,000

    const size_t need_fused = 8192 + (size_t)NB * GROUPS * SEG_CAP * 4;
    const size_t need_r12   = (size_t)256 * CSTR * 4
                              + (size_t)NB * CAP * 4;

    if (ws_size >= need_fused && N <= NB * BIN_W
        && E <= (GROUPS << GSHIFT) * K_BATCH) {
        // tier 1: fused producer-consumer overlap
        unsigned* cur  = (unsigned*)d_ws;              // [0, 4KB)
        unsigned* done = cur + 1024;                   // [4KB, 8KB)
        unsigned* bins = cur + 2048;                   // [8KB, ...)

        init_fused<<<8, 256, 0, stream>>>(cur);
        fused_sort_reduce<<<NB + NPROD, NTHREADS, 0, stream>>>(
            theta, (const int4*)src, (const int4*)dst,
            bins, cur, done, v0p, w0p, out, N, E);
    } else if (ws_size >= need_r12 && N <= NB * BIN_W) {
        // tier 2: proven R12 two-kernel path (268 us)
        unsigned* cursor = (unsigned*)d_ws;
        unsigned* bins   = cursor + 256 * CSTR;
        const int nblk   = (E + K_BATCH - 1) / K_BATCH;
        const int nbins  = (N + BIN_W - 1) / BIN_W;

        init_cursors<<<1, 256, 0, stream>>>(cursor, CSTR);
        bin_edges_sort<<<nblk, 256, 0, stream>>>(theta, (const int4*)src,
                                                 (const int4*)dst,
                                                 bins, cursor, E, CSTR);
        reduce_bins<<<nbins, 1024, 0, stream>>>(theta, bins, cursor,
                                                v0p, w0p, out, N, CSTR);
    } else {
        float2* acc = (float2*)d_ws;
        {
            const int n4 = (2 * N) / 4;
            zero_ws_kernel<<<(n4 + 255) / 256, 256, 0, stream>>>((float4*)d_ws, n4);
        }
        {
            const int E8 = E / 8;
            edge_kernel_fb<<<(E8 + 255) / 256, 256, 0, stream>>>(
                theta, (const int4*)src, (const int4*)dst, acc, E8);
        }
        node_kernel_fb<<<(N + 255) / 256, 256, 0, stream>>>(theta, acc, v0p, w0p,
                                                            out, N);
    }
}